// Round 14
// baseline (623.777 us; speedup 1.0000x reference)
//
#include <hip/hip_runtime.h>
#include <math.h>

#define BB 512
#define HH 512
#define KK 6
#define TT 60
#define OO 2
#define H2 1024
#define TO 120
#define RFP 520   // padded LDS row stride (bf16 elems), 1040B = 65x16B
#define HSP 1032  // padded h row stride (bf16 elems)

typedef __bf16 bf16x8 __attribute__((ext_vector_type(8)));
typedef float  f32x4  __attribute__((ext_vector_type(4)));
typedef float  f32x16 __attribute__((ext_vector_type(16)));

__device__ __forceinline__ float bf2f(unsigned short u) {
    union { unsigned int i; float f; } v; v.i = ((unsigned int)u) << 16; return v.f;
}
__device__ __forceinline__ unsigned short f2bf(float f) {
    union { float f; unsigned int i; } v; v.f = f;
    unsigned int b = v.i;
    return (unsigned short)((b + 0x7FFFu + ((b >> 16) & 1u)) >> 16); // RNE
}
__device__ __forceinline__ float gelu_exact(float x) {
    return 0.5f * x * (1.0f + erff(x * 0.70710678118654752f));
}

#if defined(__has_builtin)
#  if __has_builtin(__builtin_amdgcn_rcpf)
#    define FAST_RCP(x) __builtin_amdgcn_rcpf(x)
#  endif
#  if __has_builtin(__builtin_amdgcn_exp2f)
#    define FAST_EXP2(x) __builtin_amdgcn_exp2f(x)
#  endif
#endif
#ifndef FAST_RCP
#  define FAST_RCP(x) (1.0f / (x))
#endif
#ifndef FAST_EXP2
#  define FAST_EXP2(x) __expf((x) * 0.69314718056f)
#endif

// tanh-form GELU, constants pre-scaled by log2(e); ~7 VALU inst, err ~3e-4.
__device__ __forceinline__ float gelu_cheap(float x) {
    float x2 = x * x;
    float z = x * fmaf(0.10294324f, x2, 2.3022082f);
    float e = FAST_EXP2(-z);
    return x * FAST_RCP(1.0f + e);
}

struct F8 { float v[8]; };
__device__ __forceinline__ F8 load8f(const float* p) {
    F8 r;
    float4 a = *(const float4*)p;
    float4 b = *(const float4*)(p + 4);
    r.v[0] = a.x; r.v[1] = a.y; r.v[2] = a.z; r.v[3] = a.w;
    r.v[4] = b.x; r.v[5] = b.y; r.v[6] = b.z; r.v[7] = b.w;
    return r;
}
__device__ __forceinline__ F8 load8b(const unsigned short* p) {
    ushort4 a = *(const ushort4*)p;
    ushort4 b = *(const ushort4*)(p + 4);
    F8 r;
    r.v[0] = bf2f(a.x); r.v[1] = bf2f(a.y); r.v[2] = bf2f(a.z); r.v[3] = bf2f(a.w);
    r.v[4] = bf2f(b.x); r.v[5] = bf2f(b.y); r.v[6] = bf2f(b.z); r.v[7] = bf2f(b.w);
    return r;
}

// ---- fused transpose: 8 weight tensors fp32 [F][N](xZ) -> bf16 [N][F], one launch ----
struct TD { const float* src; unsigned short* dst; int F, N, tiles; };
struct TD8 { TD e[8]; };

__global__ void k_trans_all(TD8 d) {
    __shared__ unsigned short t[32][33];
    int idx = blockIdx.x;
    int i = 0;
    while (i < 7 && idx >= d.e[i].tiles) { idx -= d.e[i].tiles; ++i; }
    const int F = d.e[i].F, N = d.e[i].N;
    const int tx = F >> 5, ty = (N + 31) >> 5;
    const int per = tx * ty;
    const int z = idx / per; idx -= z * per;
    const int fx = (idx % tx) * 32, ny = (idx / tx) * 32;
    const float* src = d.e[i].src + (size_t)z * F * N;
    unsigned short* dst = d.e[i].dst + (size_t)z * F * N;
    const int r = threadIdx.x / 32, c = threadIdx.x % 32;
#pragma unroll
    for (int q = 0; q < 4; ++q) {
        int fr = fx + r + 8 * q;
        if (ny + c < N) t[r + 8 * q][c] = f2bf(src[(size_t)fr * N + ny + c]);
    }
    __syncthreads();
#pragma unroll
    for (int q = 0; q < 4; ++q) {
        int nr = ny + r + 8 * q;
        if (nr < N) dst[(size_t)nr * F + fx + c] = t[c][r + 8 * q];
    }
}

// --------- MFMA ctx-chain GEMM: C(512x512 bf16) = [gelu](A @ B + bias) ---------
template <bool CONCAT, bool GELU>
__launch_bounds__(256)
__global__ void k_gemm_m(const void* __restrict__ A0, const void* __restrict__ A1,
                         const void* __restrict__ A2, const unsigned short* __restrict__ BT,
                         const float* __restrict__ bias, unsigned short* __restrict__ C,
                         int Kd) {
    __shared__ __align__(16) unsigned short As[32 * RFP];
    const int tid = threadIdx.x;
    const int bm = blockIdx.x * 32;
    const int bn = blockIdx.y * 64;
    const int w = tid >> 6, ln = tid & 63;
    const int lane15 = ln & 15, quad = ln >> 4;
    const int n = bn + w * 16 + lane15;
    const int nchunks = Kd / HH;

    f32x4 acc0 = {0.f, 0.f, 0.f, 0.f}, acc1 = {0.f, 0.f, 0.f, 0.f};

    for (int kc = 0; kc < nchunks; ++kc) {
        {
            int r = tid >> 3, c0 = (tid & 7) * 64;
            unsigned short* dp = As + r * RFP + c0;
            if (CONCAT) {
                const float* src = (kc == 0) ? (const float*)A0
                                 : (kc == 1) ? (const float*)A1 : (const float*)A2;
                const float* sp = src + (bm + r) * HH + c0;
                for (int c = 0; c < 64; c += 8) {
                    F8 v = load8f(sp + c);
                    unsigned int pk[4];
#pragma unroll
                    for (int j = 0; j < 4; ++j)
                        pk[j] = (unsigned int)f2bf(v.v[2 * j]) |
                                ((unsigned int)f2bf(v.v[2 * j + 1]) << 16);
                    *(uint4*)(dp + c) = make_uint4(pk[0], pk[1], pk[2], pk[3]);
                }
            } else {
                const unsigned short* sp = (const unsigned short*)A0 + (bm + r) * HH + c0;
                for (int c = 0; c < 64; c += 8)
                    *(uint4*)(dp + c) = *(const uint4*)(sp + c);
            }
        }
        __syncthreads();
        const unsigned short* bp = BT + (size_t)n * Kd + kc * HH + quad * 8;
        for (int f0 = 0; f0 < HH; f0 += 32) {
            bf16x8 a0 = *(const bf16x8*)(As + lane15 * RFP + f0 + quad * 8);
            bf16x8 a1 = *(const bf16x8*)(As + (16 + lane15) * RFP + f0 + quad * 8);
            bf16x8 bf = *(const bf16x8*)(bp + f0);
            acc0 = __builtin_amdgcn_mfma_f32_16x16x32_bf16(a0, bf, acc0, 0, 0, 0);
            acc1 = __builtin_amdgcn_mfma_f32_16x16x32_bf16(a1, bf, acc1, 0, 0, 0);
        }
        __syncthreads();
    }
    const float bb = bias[n];
#pragma unroll
    for (int reg = 0; reg < 4; ++reg) {
        float v0 = acc0[reg] + bb, v1 = acc1[reg] + bb;
        if (GELU) { v0 = gelu_exact(v0); v1 = gelu_exact(v1); }
        C[(bm + quad * 4 + reg) * HH + n] = f2bf(v0);
        C[(bm + 16 + quad * 4 + reg) * HH + n] = f2bf(v1);
    }
}

// ---------------- k_bc: batched coarse-heads + conf, per (k, 16 b-rows), 8 waves ----------------
__launch_bounds__(512)
__global__ void k_bc(const unsigned short* __restrict__ ctx, const float* __restrict__ mq,
                     const unsigned short* __restrict__ Wk1T, const float* __restrict__ bk1,
                     const unsigned short* __restrict__ Wk2T, const float* __restrict__ bk2,
                     const unsigned short* __restrict__ Wf1T, const float* __restrict__ bf1,
                     const float* __restrict__ Wf2, const float* __restrict__ bf2v,
                     unsigned short* __restrict__ coarse_out, float* __restrict__ conf_out)
{
    __shared__ __align__(16) unsigned short mf[16 * RFP];   // 16,640 B
    __shared__ __align__(16) unsigned short hs[16 * HSP];   // 33,024 B

    const int tid = threadIdx.x;
    const int k = blockIdx.x % KK;
    const int b0 = (blockIdx.x / KK) * 16;
    const int w = tid >> 6;
    const int ln = tid & 63;
    const int lane15 = ln & 15;
    const int quad = ln >> 4;

    // ---- stage mf = bf16(ctx + mq[k]) rows b0..b0+15 ----
    {
        int r = tid >> 5;               // 0..15
        int c0 = (tid & 31) * 16;
        const unsigned short* cp = ctx + (b0 + r) * HH + c0;
        const float* qp = mq + k * HH + c0;
        unsigned short* dp = mf + r * RFP + c0;
        for (int c = 0; c < 16; c += 8) {
            F8 cv = load8b(cp + c);
            F8 qv = load8f(qp + c);
            unsigned int pk[4];
#pragma unroll
            for (int j = 0; j < 4; ++j)
                pk[j] = (unsigned int)f2bf(cv.v[2 * j] + qv.v[2 * j]) |
                        ((unsigned int)f2bf(cv.v[2 * j + 1] + qv.v[2 * j + 1]) << 16);
            *(uint4*)(dp + c) = make_uint4(pk[0], pk[1], pk[2], pk[3]);
        }
    }
    __syncthreads();

    // ---- GEMM1: h = gelu(mf @ Wk1[k] + bk1[k]) -> hs. Per-wave n-slice 128. ----
    {
        const unsigned short* wk1t = Wk1T + (size_t)k * H2 * HH;
        const float* bk1p = bk1 + k * H2;
        for (int g = 0; g < 8; ++g) {
            const int n = w * 128 + g * 16 + lane15;
            f32x4 acc0 = {0.f,0.f,0.f,0.f};
            const unsigned short* bp = wk1t + (size_t)n * HH + quad * 8;
            for (int f0 = 0; f0 < HH; f0 += 32) {
                bf16x8 a0 = *(const bf16x8*)(mf + lane15 * RFP + f0 + quad * 8);
                bf16x8 bf = *(const bf16x8*)(bp + f0);
                acc0 = __builtin_amdgcn_mfma_f32_16x16x32_bf16(a0, bf, acc0, 0, 0, 0);
            }
            const float bias = bk1p[n];
#pragma unroll
            for (int reg = 0; reg < 4; ++reg)
                hs[(quad * 4 + reg) * HSP + n] = f2bf(gelu_exact(acc0[reg] + bias));
        }
    }
    __syncthreads();

    // ---- GEMM2: coarse = h @ Wk2[k] + bk2[k]. Per-wave n-tile 16. ----
    {
        const unsigned short* wk2t = Wk2T + (size_t)k * TO * H2;
        const int n = w * 16 + lane15;
        const int nc = (n < TO) ? n : (TO - 1);
        f32x4 acc0 = {0.f,0.f,0.f,0.f};
        const unsigned short* bp = wk2t + (size_t)nc * H2 + quad * 8;
        for (int f0 = 0; f0 < H2; f0 += 32) {
            bf16x8 a0 = *(const bf16x8*)(hs + lane15 * HSP + f0 + quad * 8);
            bf16x8 bf = *(const bf16x8*)(bp + f0);
            acc0 = __builtin_amdgcn_mfma_f32_16x16x32_bf16(a0, bf, acc0, 0, 0, 0);
        }
        if (n < TO) {
            const float bias = bk2[k * TO + n];
#pragma unroll
            for (int reg = 0; reg < 4; ++reg)
                coarse_out[((b0 + quad * 4 + reg) * KK + k) * TO + n] = f2bf(acc0[reg] + bias);
        }
    }

    // ---- GEMM3 (wave 0): conf = relu(mf @ Wf1 + bf1) @ Wf2 + bf2 ----
    if (w == 0) {
        f32x4 acc[4];
#pragma unroll
        for (int nt = 0; nt < 4; ++nt) { f32x4 z = {0.f,0.f,0.f,0.f}; acc[nt] = z; }
        for (int f0 = 0; f0 < HH; f0 += 32) {
            bf16x8 a0 = *(const bf16x8*)(mf + lane15 * RFP + f0 + quad * 8);
#pragma unroll
            for (int nt = 0; nt < 4; ++nt) {
                const int n = nt * 16 + lane15;
                bf16x8 bf = *(const bf16x8*)(Wf1T + (size_t)n * HH + f0 + quad * 8);
                acc[nt] = __builtin_amdgcn_mfma_f32_16x16x32_bf16(a0, bf, acc[nt], 0, 0, 0);
            }
        }
        const float b2 = bf2v[0];
#pragma unroll
        for (int reg = 0; reg < 4; ++reg) {
            float s = 0.f;
#pragma unroll
            for (int nt = 0; nt < 4; ++nt) {
                const int n = nt * 16 + lane15;
                s = fmaf(fmaxf(acc[nt][reg] + bf1[n], 0.f), Wf2[n], s);
            }
#pragma unroll
            for (int off = 1; off < 16; off <<= 1) s += __shfl_xor(s, off);
            if (lane15 == 0)
                conf_out[(b0 + quad * 4 + reg) * KK + k] = s + b2;
        }
    }
}

// ---------------- k_ef: per (b,k,m-half), 512 threads / 8 waves ----------------
// M-split: each block handles 32 of the 64 trajectory rows -> LDS 34 KB ->
// 4 blocks/CU x 8 waves = 32 waves/CU (100% occupancy cap) with the proven
// 512-thread shape. Phase F per wave: 1 m-tile x 2 n-tiles (2 f32x16 accs).
// Epilogue reduction structure identical to the round-11-verified version.
__launch_bounds__(512, 4)
__global__ void k_ef(
    const unsigned short* __restrict__ attn, const unsigned short* __restrict__ coarse_ws,
    const float* __restrict__ Wt,  const float* __restrict__ bt,
    const float* __restrict__ lng, const float* __restrict__ lnb,
    const unsigned short* __restrict__ Wr1T, const float* __restrict__ br1,
    const float* __restrict__ Wr2, const float* __restrict__ br2,
    float* __restrict__ pred_out)
{
    __shared__ __align__(16) unsigned short rf[32 * RFP];   // 33,280 B
    __shared__ float coarse[TO];
    __shared__ float po[32][2];

    const int tid = threadIdx.x;
    const int idx = blockIdx.x;
    const int b   = idx / (KK * 2);
    const int rem = idx - b * (KK * 2);
    const int k   = rem >> 1;
    const int mh  = rem & 1;         // m-half: global rows mh*32 .. mh*32+31
    const int w = tid >> 6;          // 0..7
    const int ln = tid & 63;

    const unsigned short* attb = attn + b * HH;

    if (tid < TO) coarse[tid] = bf2f(coarse_ws[(b * KK + k) * TO + tid]);
    if (tid >= 128 && tid < 192) ((float*)po)[tid - 128] = 0.f;
    __syncthreads();

    // ---- Phase E: traj=gelu(coarse@Wt+bt); rf = LN(traj+attn)*g+b (bf16). 4 rows/wave. ----
    {
        const int cbase = ln * 8;
        F8 w0 = load8f(Wt + cbase);
        F8 w1 = load8f(Wt + HH + cbase);
        F8 b8 = load8f(bt + cbase);
        F8 g8 = load8f(lng + cbase);
        F8 bb8 = load8f(lnb + cbase);
        F8 a8 = load8b(attb + cbase);
#pragma unroll
        for (int r = 0; r < 4; ++r) {
            int lr = w + 8 * r;          // local row 0..31
            int t = mh * 32 + lr;        // global trajectory row
            if (t < 60) {
                float co0 = coarse[2 * t], co1 = coarse[2 * t + 1];
                float x[8]; float s = 0.f, s2 = 0.f;
#pragma unroll
                for (int j = 0; j < 8; ++j) {
                    float vv = fmaf(co0, w0.v[j], fmaf(co1, w1.v[j], b8.v[j]));
                    vv = gelu_cheap(vv) + a8.v[j];
                    x[j] = vv; s += vv; s2 = fmaf(vv, vv, s2);
                }
#pragma unroll
                for (int off = 32; off > 0; off >>= 1) {
                    s += __shfl_xor(s, off);
                    s2 += __shfl_xor(s2, off);
                }
                float mean = s * (1.0f / HH);
                float var = fmaf(-mean, mean, s2 * (1.0f / HH));
                float inv = rsqrtf(var + 1e-5f);
                unsigned int pk[4];
#pragma unroll
                for (int j = 0; j < 4; ++j) {
                    float y0 = fmaf((x[2 * j] - mean) * inv, g8.v[2 * j], bb8.v[2 * j]);
                    float y1 = fmaf((x[2 * j + 1] - mean) * inv, g8.v[2 * j + 1], bb8.v[2 * j + 1]);
                    pk[j] = (unsigned int)f2bf(y0) | ((unsigned int)f2bf(y1) << 16);
                }
                *(uint4*)(rf + lr * RFP + cbase) = make_uint4(pk[0], pk[1], pk[2], pk[3]);
            } else {
                *(uint4*)(rf + lr * RFP + cbase) = make_uint4(0, 0, 0, 0);
            }
        }
    }
    __syncthreads();

    // ---- Phase F: r=gelu(rf@Wr1+br1); offsets=r@Wr2  (32x32x16 MFMA) ----
    // A[m=lane&31][k=hf*8+j], B[n=lane&31][k=hf*8+j],
    // C/D col=lane&31, row=(reg&3)+8*(reg>>2)+4*hf  [m74/m101]
    {
        const unsigned short* wr1t_k = Wr1T + (size_t)k * HH * HH;
        const int lane31 = ln & 31;
        const int hf = ln >> 5;
        const int n0 = w * 64;           // n-chunk base: 0,64,...,448
        const unsigned short* ap = rf + (size_t)lane31 * RFP + hf * 8;
        const unsigned short* b0p = wr1t_k + (size_t)(n0 + lane31) * HH + hf * 8;
        const unsigned short* b1p = b0p + (size_t)32 * HH;

        f32x16 acc0 = {0.f,0.f,0.f,0.f,0.f,0.f,0.f,0.f,0.f,0.f,0.f,0.f,0.f,0.f,0.f,0.f};
        f32x16 acc1 = acc0;

#pragma unroll 2
        for (int k0 = 0; k0 < HH; k0 += 16) {
            bf16x8 A  = *(const bf16x8*)(ap + k0);
            bf16x8 B0 = *(const bf16x8*)(b0p + k0);
            bf16x8 B1 = *(const bf16x8*)(b1p + k0);
            acc0 = __builtin_amdgcn_mfma_f32_32x32x16_bf16(A, B0, acc0, 0, 0, 0);
            acc1 = __builtin_amdgcn_mfma_f32_32x32x16_bf16(A, B1, acc1, 0, 0, 0);
        }

        const int col0 = n0 + lane31;
        const int col1 = col0 + 32;
        const float bb0 = br1[k * HH + col0];
        const float bb1v = br1[k * HH + col1];
        const float v200 = Wr2[(size_t)(k * HH + col0) * 2];
        const float v201 = Wr2[(size_t)(k * HH + col0) * 2 + 1];
        const float v210 = Wr2[(size_t)(k * HH + col1) * 2];
        const float v211 = Wr2[(size_t)(k * HH + col1) * 2 + 1];

        float p0[16], p1[16];
#pragma unroll
        for (int reg = 0; reg < 16; ++reg) {
            float rv0 = gelu_cheap(acc0[reg] + bb0);
            float rv1 = gelu_cheap(acc1[reg] + bb1v);
            p0[reg] = fmaf(rv0, v200, rv1 * v210);
            p1[reg] = fmaf(rv0, v201, rv1 * v211);
        }
#pragma unroll
        for (int off = 1; off < 32; off <<= 1) {
#pragma unroll
            for (int reg = 0; reg < 16; ++reg) {
                p0[reg] += __shfl_xor(p0[reg], off);
                p1[reg] += __shfl_xor(p1[reg], off);
            }
        }
        if (lane31 == 0) {
#pragma unroll
            for (int reg = 0; reg < 16; ++reg) {
                int row = (reg & 3) + 8 * (reg >> 2) + 4 * hf;   // local row 0..31
                atomicAdd(&po[row][0], p0[reg]);
                atomicAdd(&po[row][1], p1[reg]);
            }
        }
    }
    __syncthreads();

    if (tid < 64) {
        int lr = tid >> 1, o = tid & 1;
        int t = mh * 32 + lr;
        if (t < TT) {
            float v = coarse[t * 2 + o] + po[lr][o] + br2[k * 2 + o];
            pred_out[((b * KK + k) * TT + t) * 2 + o] = v;
        }
    }
}

// ---------------- softmax over K for mode_probs ----------------
__global__ void k_softmax(const float* __restrict__ conf, float* __restrict__ out) {
    int b = blockIdx.x * blockDim.x + threadIdx.x;
    if (b < BB) {
        float v[KK];
        float m = -1e30f;
        for (int i = 0; i < KK; ++i) { v[i] = conf[b * KK + i]; m = fmaxf(m, v[i]); }
        float s = 0.f;
        for (int i = 0; i < KK; ++i) { v[i] = __expf(v[i] - m); s += v[i]; }
        float inv = 1.0f / s;
        for (int i = 0; i < KK; ++i) out[b * KK + i] = v[i] * inv;
    }
}

extern "C" void kernel_launch(void* const* d_in, const int* in_sizes, int n_in,
                              void* d_out, int out_size, void* d_ws, size_t ws_size,
                              hipStream_t stream) {
    const float* I0  = (const float*)d_in[0];
    const float* I1  = (const float*)d_in[1];
    const float* I2  = (const float*)d_in[2];
    const float* MQ  = (const float*)d_in[3];
    const float* Wc1 = (const float*)d_in[4];
    const float* bc1 = (const float*)d_in[5];
    const float* Wc2 = (const float*)d_in[6];
    const float* bc2 = (const float*)d_in[7];
    const float* Wk1 = (const float*)d_in[8];
    const float* bk1 = (const float*)d_in[9];
    const float* Wk2 = (const float*)d_in[10];
    const float* bk2 = (const float*)d_in[11];
    const float* Wt  = (const float*)d_in[12];
    const float* bt  = (const float*)d_in[13];
    const float* Wv  = (const float*)d_in[18];
    const float* bv  = (const float*)d_in[19];
    const float* Wo  = (const float*)d_in[20];
    const float* bo  = (const float*)d_in[21];
    const float* lng = (const float*)d_in[22];
    const float* lnb = (const float*)d_in[23];
    const float* Wr1 = (const float*)d_in[24];
    const float* br1 = (const float*)d_in[25];
    const float* Wr2 = (const float*)d_in[26];
    const float* br2 = (const float*)d_in[27];
    const float* Wf1 = (const float*)d_in[28];
    const float* bf1 = (const float*)d_in[29];
    const float* Wf2 = (const float*)d_in[30];
    const float* bf2v = (const float*)d_in[31];

    unsigned short* wsu   = (unsigned short*)d_ws;
    unsigned short* wc1t  = wsu;                 // 786,432   [512][1536]
    unsigned short* wc2t  = wsu + 786432;        // 262,144
    unsigned short* wvt   = wsu + 1048576;       // 262,144
    unsigned short* wot   = wsu + 1310720;       // 262,144
    unsigned short* wk1t  = wsu + 1572864;       // 3,145,728 (K)[1024][512]
    unsigned short* wk2t  = wsu + 4718592;       // 737,280   (K)[120][1024]
    unsigned short* wf1t  = wsu + 5455872;       // 32,768    [64][512]
    unsigned short* wr1t  = wsu + 5488640;       // 1,572,864 (K)[512][512]
    unsigned short* ctx   = wsu + 7061504;       // 262,144
    unsigned short* attn  = wsu + 7323648;       // 262,144
    unsigned short* tmp   = wsu + 7585792;       // 262,144 (g1 / vbuf)
    unsigned short* coarse= wsu + 7847936;       // 368,640 (B,K,120)
    float* conf = (float*)(wsu + 8216576);       // 3072 fp32

    float* pred = (float*)d_out;
    float* probs = pred + BB * KK * TT * OO;

    // -- prep: all weights -> bf16 [n][f], single launch --
    TD8 td;
    td.e[0] = {Wc1, wc1t, 3 * HH, HH, 768};
    td.e[1] = {Wc2, wc2t, HH, HH, 256};
    td.e[2] = {Wv,  wvt,  HH, HH, 256};
    td.e[3] = {Wo,  wot,  HH, HH, 256};
    td.e[4] = {Wk1, wk1t, HH, H2, 3072};
    td.e[5] = {Wk2, wk2t, H2, TO, 768};
    td.e[6] = {Wf1, wf1t, HH, 64, 32};
    td.e[7] = {Wr1, wr1t, HH, HH, 1536};
    k_trans_all<<<dim3(6944), 256, 0, stream>>>(td);

    // -- ctx chain --
    k_gemm_m<true,  true ><<<dim3(16, 8), 256, 0, stream>>>(I0, I1, I2, wc1t, bc1, tmp, 3 * HH);
    k_gemm_m<false, false><<<dim3(16, 8), 256, 0, stream>>>(tmp, nullptr, nullptr, wc2t, bc2, ctx, HH);
    k_gemm_m<false, false><<<dim3(16, 8), 256, 0, stream>>>(ctx, nullptr, nullptr, wvt, bv, tmp, HH);
    k_gemm_m<false, false><<<dim3(16, 8), 256, 0, stream>>>(tmp, nullptr, nullptr, wot, bo, attn, HH);

    k_bc<<<dim3(192), 512, 0, stream>>>(ctx, MQ, wk1t, bk1, wk2t, bk2, wf1t, bf1, Wf2, bf2v,
                                        coarse, conf);
    k_ef<<<dim3(BB * KK * 2), 512, 0, stream>>>(attn, coarse, Wt, bt, lng, lnb,
                                                wr1t, br1, Wr2, br2, pred);
    k_softmax<<<dim3(2), 256, 0, stream>>>(conf, probs);
}